// Round 2
// baseline (291.325 us; speedup 1.0000x reference)
//
#include <hip/hip_runtime.h>

// (B,C,H,W)=(32,32,64,64), D=32, K=512
#define C_    32
#define D_    32
#define K_    512
#define HW_   4096
#define NTOK  131072
#define OUT_ELEMS 4194304
#define IDX_OFF   4194304
#define LOSS_OFF  4325376
#define TPB   64      // tokens per block
#define KQ    128     // codes scanned per wave (K_/4)
#define XS    36      // padded LDS row stride (floats), multiple of 4

// one-time codebook squared norms into workspace
__global__ void cb_norms(const float* __restrict__ cb, float* __restrict__ cbn) {
    const int k = blockIdx.x * 64 + threadIdx.x;
    const float* row = cb + k * D_;
    float s = 0.f;
    #pragma unroll
    for (int d = 0; d < D_; ++d) s = fmaf(row[d], row[d], s);
    cbn[k] = s;
}

__global__ __launch_bounds__(256)
void vq_fused(const float* __restrict__ z,  const float* __restrict__ qw,
              const float* __restrict__ qb, const float* __restrict__ cb,
              const float* __restrict__ pw, const float* __restrict__ pb,
              const float* __restrict__ cbn, float* __restrict__ out)
{
    __shared__ float xsh[TPB * XS];
    __shared__ float qsh[TPB * XS];
    __shared__ float redb[4][TPB];
    __shared__ int   redi[4][TPB];
    __shared__ float lsum[4];

    const int tid  = threadIdx.x;
    const int w    = tid >> 6;        // wave id 0..3 (= K quarter, = channel group)
    const int lane = tid & 63;        // token within block
    const int token = blockIdx.x * TPB + lane;
    const int b  = token >> 12;
    const int hw = token & (HW_ - 1);

    const float* zbase = z + (size_t)b * (C_ * HW_) + hw;

    // ---- load z channels for this token (coalesced across lanes; L1-shared across waves) ----
    float zv[C_];
    #pragma unroll
    for (int c = 0; c < C_; ++c) zv[c] = zbase[(size_t)c * HW_];

    // ---- quant conv, split: wave w computes xf[d] for d in [8w, 8w+8) ----
    float xp[8];
    #pragma unroll
    for (int i = 0; i < 8; ++i) {
        const int d = (w << 3) + i;
        float a = qb[d];
        const float* qr = qw + d * C_;
        #pragma unroll
        for (int c = 0; c < C_; ++c) a = fmaf(zv[c], qr[c], a);
        xp[i] = a;
    }
    {   // share via LDS (two aligned float4 stores)
        float* p = xsh + lane * XS + (w << 3);
        *(float4*)(p)     = make_float4(xp[0], xp[1], xp[2], xp[3]);
        *(float4*)(p + 4) = make_float4(xp[4], xp[5], xp[6], xp[7]);
    }
    __syncthreads();

    // ---- full xf into registers ----
    float xf[D_];
    #pragma unroll
    for (int j = 0; j < D_; j += 4) {
        const float4 v = *(const float4*)(xsh + lane * XS + j);
        xf[j] = v.x; xf[j+1] = v.y; xf[j+2] = v.z; xf[j+3] = v.w;
    }

    // ---- distance scan: wave w covers k in [kbase, kbase+KQ) ----
    const int kbase = w * KQ;
    const float* crow = cb + (size_t)kbase * D_;
    float best = 3.4e38f;
    int   bi   = 0;
    #pragma unroll 4
    for (int kk = 0; kk < KQ; ++kk) {
        const float* row = crow + kk * D_;   // wave-uniform -> s_load path
        float p0 = 0.f, p1 = 0.f, p2 = 0.f, p3 = 0.f;
        #pragma unroll
        for (int d = 0; d < D_; d += 4) {
            p0 = fmaf(xf[d + 0], row[d + 0], p0);
            p1 = fmaf(xf[d + 1], row[d + 1], p1);
            p2 = fmaf(xf[d + 2], row[d + 2], p2);
            p3 = fmaf(xf[d + 3], row[d + 3], p3);
        }
        const float s = fmaf(-2.f, (p0 + p1) + (p2 + p3), cbn[kbase + kk]);
        if (s < best) { best = s; bi = kk; }   // strict <: first min within quarter
    }
    redb[w][lane] = best;
    redi[w][lane] = kbase + bi;
    __syncthreads();

    // ---- combine quarters (wave 0), write idx, gather chosen code to LDS ----
    if (w == 0) {
        float bb = redb[0][lane];
        int   ib = redi[0][lane];
        #pragma unroll
        for (int q = 1; q < 4; ++q) {
            const float v = redb[q][lane];
            if (v < bb) { bb = v; ib = redi[q][lane]; }  // tie -> lower quarter (jnp first-min)
        }
        out[IDX_OFF + token] = (float)ib;
        const float* qr = cb + (size_t)ib * D_;
        float* p = qsh + lane * XS;
        #pragma unroll
        for (int j = 0; j < D_; j += 4)
            *(float4*)(p + j) = *(const float4*)(qr + j);
    }
    __syncthreads();

    // ---- loss partial: this wave's 8 channels (xp == xf[8w..8w+8)) ----
    float l = 0.f;
    {
        const float* p = qsh + lane * XS + (w << 3);
        #pragma unroll
        for (int i = 0; i < 8; ++i) {
            const float df = p[i] - xp[i];
            l = fmaf(df, df, l);
        }
    }
    #pragma unroll
    for (int off = 32; off; off >>= 1) l += __shfl_down(l, off);
    if (lane == 0) lsum[w] = l;

    // ---- post conv, split: wave w computes out channels [8w, 8w+8) ----
    float qv[D_];
    #pragma unroll
    for (int j = 0; j < D_; j += 4) {
        const float4 v = *(const float4*)(qsh + lane * XS + j);
        qv[j] = v.x; qv[j+1] = v.y; qv[j+2] = v.z; qv[j+3] = v.w;
    }
    float* obase = out + (size_t)b * (C_ * HW_) + hw;
    #pragma unroll
    for (int i = 0; i < 8; ++i) {
        const int c = (w << 3) + i;
        float a = pb[c];
        const float* pr = pw + c * D_;
        #pragma unroll
        for (int d = 0; d < D_; ++d) a = fmaf(qv[d], pr[d], a);
        obase[(size_t)c * HW_] = a;
    }

    __syncthreads();   // lsum ready
    if (tid == 0) {
        const float t = (lsum[0] + lsum[1]) + (lsum[2] + lsum[3]);
        atomicAdd(out + LOSS_OFF, t * (2.0f / (float)(NTOK * D_)));
    }
}

extern "C" void kernel_launch(void* const* d_in, const int* in_sizes, int n_in,
                              void* d_out, int out_size, void* d_ws, size_t ws_size,
                              hipStream_t stream) {
    (void)in_sizes; (void)n_in; (void)ws_size; (void)out_size;
    const float* z  = (const float*)d_in[0];
    const float* qw = (const float*)d_in[1];
    const float* qb = (const float*)d_in[2];
    const float* cb = (const float*)d_in[3];
    const float* pw = (const float*)d_in[4];
    const float* pb = (const float*)d_in[5];
    float* out = (float*)d_out;
    float* cbn = (float*)d_ws;   // 512 floats

    hipMemsetAsync((char*)d_out + (size_t)LOSS_OFF * sizeof(float), 0, sizeof(float), stream);
    cb_norms<<<K_ / 64, 64, 0, stream>>>(cb, cbn);
    vq_fused<<<NTOK / TPB, 256, 0, stream>>>(z, qw, qb, cb, pw, pb, cbn, out);
}

// Round 3
// 125.481 us; speedup vs baseline: 2.3217x; 2.3217x over previous
//
#include <hip/hip_runtime.h>

// (B,C,H,W)=(32,32,64,64), D=32, K=512
#define C_    32
#define D_    32
#define K_    512
#define HW_   4096
#define NTOK  131072
#define OUT_ELEMS 4194304
#define IDX_OFF   4194304
#define LOSS_OFF  4325376
#define NSLICE 4
#define KS    (K_ / NSLICE)       // 128 codes per slice
// ws layout (bytes): cbn @0 (2048), best @4096 (2 MB), idx @4096+2MB (2 MB)
#define WS_BEST_OFF 4096
#define WS_IDX_OFF  (4096 + NSLICE * NTOK * 4)
#define WS_NEEDED   (4096 + 2 * NSLICE * NTOK * 4)

__global__ void cb_norms(const float* __restrict__ cb, float* __restrict__ cbn) {
    const int k = blockIdx.x * 64 + threadIdx.x;
    const float* row = cb + k * D_;
    float s = 0.f;
    #pragma unroll
    for (int d = 0; d < D_; ++d) s = fmaf(row[d], row[d], s);
    cbn[k] = s;
}

// grid 2048: XCD-swizzled (tile tb, slice s); tokens tb*256+tid; codes [s*KS, s*KS+KS)
__global__ __launch_bounds__(256)
void dist_scan(const float* __restrict__ z,  const float* __restrict__ qw,
               const float* __restrict__ qb, const float* __restrict__ cb,
               const float* __restrict__ cbn,
               float* __restrict__ bestW, int* __restrict__ idxW)
{
    const int bid = blockIdx.x;
    const int x = bid & 7;            // XCD slot
    const int j = bid >> 3;           // 0..255
    const int tb = x * 64 + (j >> 2); // token tile 0..511 (64 tiles per XCD)
    const int s  = j & 3;             // K slice (blockIdx-derived -> uniform!)
    const int tid = threadIdx.x;
    const int token = tb * 256 + tid;
    const int b  = token >> 12;
    const int hw = token & (HW_ - 1);

    // z channels
    const float* zbase = z + (size_t)b * (C_ * HW_) + hw;
    float zv[C_];
    #pragma unroll
    for (int c = 0; c < C_; ++c) zv[c] = zbase[(size_t)c * HW_];

    // quant conv (qw rows via uniform s_load)
    float xf[D_];
    #pragma unroll
    for (int d = 0; d < D_; ++d) {
        float a = qb[d];
        const float* qr = qw + d * C_;
        #pragma unroll
        for (int c = 0; c < C_; ++c) a = fmaf(zv[c], qr[c], a);
        xf[d] = a;
    }

    // distance scan over this slice's codes (uniform base -> s_load rows)
    const int kbase = s * KS;
    const float* crow = cb + (size_t)kbase * D_;
    const float* cbs  = cbn + kbase;
    float best = 3.4e38f;
    int   bi   = 0;
    #pragma unroll 2
    for (int kk = 0; kk < KS; ++kk) {
        const float* row = crow + kk * D_;
        float p0 = 0.f, p1 = 0.f, p2 = 0.f, p3 = 0.f;
        #pragma unroll
        for (int d = 0; d < D_; d += 4) {
            p0 = fmaf(xf[d + 0], row[d + 0], p0);
            p1 = fmaf(xf[d + 1], row[d + 1], p1);
            p2 = fmaf(xf[d + 2], row[d + 2], p2);
            p3 = fmaf(xf[d + 3], row[d + 3], p3);
        }
        const float sd = fmaf(-2.f, (p0 + p1) + (p2 + p3), cbs[kk]);
        if (sd < best) { best = sd; bi = kk; }  // strict <: first min within slice
    }
    bestW[s * NTOK + token] = best;
    idxW [s * NTOK + token] = kbase + bi;
}

// grid 512 (same XCD mapping): combine slices, idx, loss, post conv
__global__ __launch_bounds__(256)
void combine(const float* __restrict__ z,  const float* __restrict__ qw,
             const float* __restrict__ qb, const float* __restrict__ cb,
             const float* __restrict__ pw, const float* __restrict__ pb,
             const float* __restrict__ bestW, const int* __restrict__ idxW,
             float* __restrict__ out)
{
    __shared__ float lsum[4];
    const int bid = blockIdx.x;
    const int tb = (bid & 7) * 64 + (bid >> 3);   // match dist_scan tile->XCD
    const int tid = threadIdx.x;
    const int token = tb * 256 + tid;
    const int b  = token >> 12;
    const int hw = token & (HW_ - 1);

    // pick global min (slice-ascending, strict < => jnp first-min)
    float bb = bestW[token];
    int   ib = idxW[token];
    #pragma unroll
    for (int s = 1; s < NSLICE; ++s) {
        const float v = bestW[s * NTOK + token];
        if (v < bb) { bb = v; ib = idxW[s * NTOK + token]; }
    }
    out[IDX_OFF + token] = (float)ib;

    // recompute xf for the loss
    const float* zbase = z + (size_t)b * (C_ * HW_) + hw;
    float zv[C_];
    #pragma unroll
    for (int c = 0; c < C_; ++c) zv[c] = zbase[(size_t)c * HW_];
    float xf[D_];
    #pragma unroll
    for (int d = 0; d < D_; ++d) {
        float a = qb[d];
        const float* qr = qw + d * C_;
        #pragma unroll
        for (int c = 0; c < C_; ++c) a = fmaf(zv[c], qr[c], a);
        xf[d] = a;
    }

    // gather chosen code
    const float* qrow = cb + (size_t)ib * D_;
    float qv[D_];
    #pragma unroll
    for (int d = 0; d < D_; d += 4) {
        const float4 v = *(const float4*)(qrow + d);
        qv[d] = v.x; qv[d+1] = v.y; qv[d+2] = v.z; qv[d+3] = v.w;
    }

    // loss partial
    float l = 0.f;
    #pragma unroll
    for (int d = 0; d < D_; ++d) { const float df = qv[d] - xf[d]; l = fmaf(df, df, l); }
    #pragma unroll
    for (int off = 32; off; off >>= 1) l += __shfl_down(l, off);
    const int wid = tid >> 6, lane = tid & 63;
    if (lane == 0) lsum[wid] = l;

    // post conv
    float* obase = out + (size_t)b * (C_ * HW_) + hw;
    #pragma unroll
    for (int c = 0; c < C_; ++c) {
        float a = pb[c];
        const float* pr = pw + c * D_;
        #pragma unroll
        for (int d = 0; d < D_; ++d) a = fmaf(qv[d], pr[d], a);
        obase[(size_t)c * HW_] = a;
    }

    __syncthreads();
    if (tid == 0) {
        const float t = (lsum[0] + lsum[1]) + (lsum[2] + lsum[3]);
        atomicAdd(out + LOSS_OFF, t * (2.0f / (float)(NTOK * D_)));
    }
}

// fallback (round-1 monolithic, used only if ws_size is too small)
__global__ __launch_bounds__(256)
void vq_mono(const float* __restrict__ z,  const float* __restrict__ qw,
             const float* __restrict__ qb, const float* __restrict__ cb,
             const float* __restrict__ pw, const float* __restrict__ pb,
             float* __restrict__ out)
{
    __shared__ float cbn_s[K_];
    __shared__ float lsum[4];
    const int tid = threadIdx.x;
    for (int k = tid; k < K_; k += 256) {
        const float* row = cb + k * D_;
        float s = 0.f;
        #pragma unroll
        for (int d = 0; d < D_; ++d) s = fmaf(row[d], row[d], s);
        cbn_s[k] = s;
    }
    __syncthreads();
    const int token = blockIdx.x * 256 + tid;
    const int b = token >> 12, hw = token & (HW_ - 1);
    const float* zbase = z + (size_t)b * C_ * HW_ + hw;
    float zv[C_];
    #pragma unroll
    for (int c = 0; c < C_; ++c) zv[c] = zbase[(size_t)c * HW_];
    float xf[D_];
    #pragma unroll
    for (int d = 0; d < D_; ++d) {
        float a = qb[d];
        #pragma unroll
        for (int c = 0; c < C_; ++c) a = fmaf(zv[c], qw[d * C_ + c], a);
        xf[d] = a;
    }
    float best = 3.4e38f; int bi = 0;
    #pragma unroll 2
    for (int k = 0; k < K_; ++k) {
        const float* row = cb + k * D_;
        float p0 = 0.f, p1 = 0.f, p2 = 0.f, p3 = 0.f;
        #pragma unroll
        for (int d = 0; d < D_; d += 4) {
            p0 = fmaf(xf[d+0], row[d+0], p0); p1 = fmaf(xf[d+1], row[d+1], p1);
            p2 = fmaf(xf[d+2], row[d+2], p2); p3 = fmaf(xf[d+3], row[d+3], p3);
        }
        const float s = fmaf(-2.f, (p0+p1)+(p2+p3), cbn_s[k]);
        if (s < best) { best = s; bi = k; }
    }
    out[IDX_OFF + token] = (float)bi;
    const float* qrow = cb + (size_t)bi * D_;
    float qv[D_];
    #pragma unroll
    for (int d = 0; d < D_; ++d) qv[d] = qrow[d];
    float l = 0.f;
    #pragma unroll
    for (int d = 0; d < D_; ++d) { const float df = qv[d] - xf[d]; l = fmaf(df, df, l); }
    float* obase = out + (size_t)b * C_ * HW_ + hw;
    #pragma unroll
    for (int c = 0; c < C_; ++c) {
        float a = pb[c];
        #pragma unroll
        for (int d = 0; d < D_; ++d) a = fmaf(qv[d], pw[c * D_ + d], a);
        obase[(size_t)c * HW_] = a;
    }
    #pragma unroll
    for (int off = 32; off; off >>= 1) l += __shfl_down(l, off);
    const int wid = tid >> 6, lane = tid & 63;
    if (lane == 0) lsum[wid] = l;
    __syncthreads();
    if (tid == 0) {
        const float t = (lsum[0] + lsum[1]) + (lsum[2] + lsum[3]);
        atomicAdd(out + LOSS_OFF, t * (2.0f / (float)(NTOK * D_)));
    }
}

extern "C" void kernel_launch(void* const* d_in, const int* in_sizes, int n_in,
                              void* d_out, int out_size, void* d_ws, size_t ws_size,
                              hipStream_t stream) {
    (void)in_sizes; (void)n_in; (void)out_size;
    const float* z  = (const float*)d_in[0];
    const float* qw = (const float*)d_in[1];
    const float* qb = (const float*)d_in[2];
    const float* cb = (const float*)d_in[3];
    const float* pw = (const float*)d_in[4];
    const float* pb = (const float*)d_in[5];
    float* out = (float*)d_out;

    hipMemsetAsync((char*)d_out + (size_t)LOSS_OFF * sizeof(float), 0, sizeof(float), stream);

    if (ws_size < (size_t)WS_NEEDED) {
        vq_mono<<<NTOK / 256, 256, 0, stream>>>(z, qw, qb, cb, pw, pb, out);
        return;
    }
    float* cbn   = (float*)d_ws;
    float* bestW = (float*)((char*)d_ws + WS_BEST_OFF);
    int*   idxW  = (int*)  ((char*)d_ws + WS_IDX_OFF);

    cb_norms<<<K_ / 64, 64, 0, stream>>>(cb, cbn);
    dist_scan<<<NTOK / 256 * NSLICE, 256, 0, stream>>>(z, qw, qb, cb, cbn, bestW, idxW);
    combine<<<NTOK / 256, 256, 0, stream>>>(z, qw, qb, cb, pw, pb, bestW, idxW, out);
}

// Round 5
// 95.151 us; speedup vs baseline: 3.0617x; 1.3188x over previous
//
#include <hip/hip_runtime.h>

// (B,C,H,W)=(32,32,64,64), D=32, K=512
#define C_    32
#define D_    32
#define K_    512
#define HW_   4096
#define NTOK  131072
#define IDX_OFF   4194304
#define LOSS_OFF  4325376
#define TAU      2e-3f     // flag threshold (>=4x worst-case approx error)
#define CONS_EPS 1e-3f     // approx-vs-exact consistency tolerance

// ws byte offsets (hand-verified, non-overlapping, 16B-aligned)
#define WS_CBN   0                 // 512 f32          -> 2048
#define WS_CBH   4096              // 512*32 bf16      -> +32768 = 36864
#define WS_CBL   36864             //                  -> +32768 = 69632
#define WS_XH    69632             // NTOK*32 bf16     -> +8388608 = 8458240
#define WS_XL    8458240           //                  -> +8388608 = 16846848
#define WS_XFT   16846848          // [32][NTOK] f32   -> +16777216 = 33624064
#define WS_IDXF  33624064          // NTOK u32         -> +524288 = 34148352
#define WS_BESTW 34148352          // NTOK f32         -> +524288 = 34672640
#define WS_NEEDED 34672640

typedef __attribute__((ext_vector_type(8))) __bf16 bf16x8;
typedef __attribute__((ext_vector_type(8))) short  short8;
typedef __attribute__((ext_vector_type(4))) float  f32x4;

__device__ inline unsigned short f2bf(float x) {          // RNE fp32->bf16
    unsigned u = __builtin_bit_cast(unsigned, x);
    return (unsigned short)((u + 0x7FFFu + ((u >> 16) & 1u)) >> 16);
}
__device__ inline float bf2f(unsigned short h) {
    unsigned u = ((unsigned)h) << 16; return __builtin_bit_cast(float, u);
}
__device__ inline bf16x8 ldfrag(const unsigned short* p) {
    return __builtin_bit_cast(bf16x8, *(const short8*)p);
}

// ---------- prep: xf (fp32, [d][token]) + bf16 hi/lo splits of xf and codebook ----------
__global__ __launch_bounds__(256)
void prep(const float* __restrict__ z,  const float* __restrict__ qw,
          const float* __restrict__ qb, const float* __restrict__ cb,
          float* __restrict__ cbn, unsigned short* __restrict__ cbh,
          unsigned short* __restrict__ cbl, unsigned short* __restrict__ xh,
          unsigned short* __restrict__ xl, float* __restrict__ xfT)
{
    const int tid = threadIdx.x;
    if (blockIdx.x == 0) {   // codebook split + norms (tiny)
        for (int k = tid; k < K_; k += 256) {
            const float* row = cb + k * D_;
            float s = 0.f; unsigned short hrow[32], lrow[32];
            #pragma unroll
            for (int d = 0; d < D_; ++d) {
                float v = row[d]; s = fmaf(v, v, s);
                unsigned short h = f2bf(v); hrow[d] = h; lrow[d] = f2bf(v - bf2f(h));
            }
            cbn[k] = s;
            #pragma unroll
            for (int j = 0; j < 4; ++j) {
                *(short8*)(cbh + k * 32 + 8 * j) = *(const short8*)(hrow + 8 * j);
                *(short8*)(cbl + k * 32 + 8 * j) = *(const short8*)(lrow + 8 * j);
            }
        }
    }
    const int token = blockIdx.x * 256 + tid;
    const int b = token >> 12, hw = token & (HW_ - 1);
    const float* zbase = z + (size_t)b * (C_ * HW_) + hw;
    float zv[C_];
    #pragma unroll
    for (int c = 0; c < C_; ++c) zv[c] = zbase[(size_t)c * HW_];
    unsigned short hrow[32], lrow[32];
    #pragma unroll
    for (int d = 0; d < D_; ++d) {
        float a = qb[d]; const float* qr = qw + d * C_;
        #pragma unroll
        for (int c = 0; c < C_; ++c) a = fmaf(zv[c], qr[c], a);
        xfT[(size_t)d * NTOK + token] = a;
        unsigned short h = f2bf(a); hrow[d] = h; lrow[d] = f2bf(a - bf2f(h));
    }
    #pragma unroll
    for (int j = 0; j < 4; ++j) {
        *(short8*)(xh + (size_t)token * 32 + 8 * j) = *(const short8*)(hrow + 8 * j);
        *(short8*)(xl + (size_t)token * 32 + 8 * j) = *(const short8*)(lrow + 8 * j);
    }
}

// ---------- scan: split-bf16 MFMA distance top-2 argmin, 32 tokens/wave ----------
__global__ __launch_bounds__(256)
void scan_mfma(const unsigned short* __restrict__ xh, const unsigned short* __restrict__ xl,
               const unsigned short* __restrict__ cbh, const unsigned short* __restrict__ cbl,
               const float* __restrict__ cbn, unsigned* __restrict__ idxf,
               float* __restrict__ bestW)
{
    const int tid = threadIdx.x;
    const int wv = tid >> 6, l = tid & 63;
    const int tile = (blockIdx.x * 4 + wv) * 32;
    const int lr = l & 15, lg = l >> 4;

    // A fragments: row = lane&15 (token), k-elems = (lane>>4)*8 + j
    const unsigned short* pa  = xh + (size_t)(tile + lr) * 32 + lg * 8;
    const unsigned short* pal = xl + (size_t)(tile + lr) * 32 + lg * 8;
    bf16x8 ah0 = ldfrag(pa),  ah1 = ldfrag(pa + 16 * 32);
    bf16x8 al0 = ldfrag(pal), al1 = ldfrag(pal + 16 * 32);

    float b1[8], b2[8]; int i1[8];
    #pragma unroll
    for (int s = 0; s < 8; ++s) { b1[s] = 3.4e38f; b2[s] = 3.4e38f; i1[s] = 0; }

    #pragma unroll 2
    for (int nt = 0; nt < 32; ++nt) {
        const size_t boff = (size_t)(nt * 16 + lr) * 32 + lg * 8;
        bf16x8 bh = ldfrag(cbh + boff);
        bf16x8 bl = ldfrag(cbl + boff);
        const float cn = cbn[nt * 16 + lr];
        f32x4 acc0 = {0.f, 0.f, 0.f, 0.f}, acc1 = {0.f, 0.f, 0.f, 0.f};
        acc0 = __builtin_amdgcn_mfma_f32_16x16x32_bf16(ah0, bh, acc0, 0, 0, 0);
        acc0 = __builtin_amdgcn_mfma_f32_16x16x32_bf16(ah0, bl, acc0, 0, 0, 0);
        acc0 = __builtin_amdgcn_mfma_f32_16x16x32_bf16(al0, bh, acc0, 0, 0, 0);
        acc1 = __builtin_amdgcn_mfma_f32_16x16x32_bf16(ah1, bh, acc1, 0, 0, 0);
        acc1 = __builtin_amdgcn_mfma_f32_16x16x32_bf16(ah1, bl, acc1, 0, 0, 0);
        acc1 = __builtin_amdgcn_mfma_f32_16x16x32_bf16(al1, bh, acc1, 0, 0, 0);
        const int n = nt * 16 + lr;
        #pragma unroll
        for (int r = 0; r < 4; ++r) {
            {   // slot r: token m = lg*4+r (C/D: row=(lane>>4)*4+reg, col=lane&15)
                const float d2 = fmaf(-2.f, acc0[r], cn);
                const bool lt1 = d2 < b1[r], lt2 = d2 < b2[r];
                b2[r] = lt1 ? b1[r] : (lt2 ? d2 : b2[r]);
                b1[r] = lt1 ? d2 : b1[r];
                i1[r] = lt1 ? n  : i1[r];
            }
            {   // slot 4+r: token 16 + lg*4+r
                const float d2 = fmaf(-2.f, acc1[r], cn);
                const bool lt1 = d2 < b1[4+r], lt2 = d2 < b2[4+r];
                b2[4+r] = lt1 ? b1[4+r] : (lt2 ? d2 : b2[4+r]);
                b1[4+r] = lt1 ? d2 : b1[4+r];
                i1[4+r] = lt1 ? n  : i1[4+r];
            }
        }
    }
    // merge top-2 across the 16 n-lanes of each group
    #pragma unroll
    for (int mk = 1; mk < 16; mk <<= 1) {
        #pragma unroll
        for (int s = 0; s < 8; ++s) {
            const float ob1 = __shfl_xor(b1[s], mk);
            const int   oi1 = __shfl_xor(i1[s], mk);
            const float ob2 = __shfl_xor(b2[s], mk);
            const bool take = (ob1 < b1[s]) || (ob1 == b1[s] && oi1 < i1[s]);
            const float loser = take ? b1[s] : ob1;
            b1[s] = take ? ob1 : b1[s];
            i1[s] = take ? oi1 : i1[s];
            b2[s] = fminf(fminf(b2[s], ob2), loser);
        }
    }
    // one writer per token
    #pragma unroll
    for (int s = 0; s < 8; ++s) {
        if (lr == s) {
            const int token = tile + (s >> 2) * 16 + lg * 4 + (s & 3);
            const bool fl = (b2[s] - b1[s]) < TAU;
            idxf[token]  = (unsigned)i1[s] | (fl ? 0x80000000u : 0u);
            bestW[token] = b1[s];
        }
    }
}

// ---------- combine: consistency-check, exact rescan of flagged, idx/loss/post-conv ----------
__global__ __launch_bounds__(256)
void combine(const float* __restrict__ cb, const float* __restrict__ pw,
             const float* __restrict__ pb, const float* __restrict__ cbn,
             const float* __restrict__ xfT, const unsigned* __restrict__ idxf,
             const float* __restrict__ bestW, float* __restrict__ out)
{
    __shared__ float lsum[4];
    const int tid = threadIdx.x;
    const int token = blockIdx.x * 256 + tid;
    const int b = token >> 12, hw = token & (HW_ - 1);
    const int lane = tid & 63;

    const unsigned pf = idxf[token];
    int idx = (int)(pf & 511u);
    int flag = (int)(pf >> 31);

    float xf[D_];
    #pragma unroll
    for (int d = 0; d < D_; ++d) xf[d] = xfT[(size_t)d * NTOK + token];

    // consistency check: exact fp32 distance of approx pick must match bestW
    {
        const float* row = cb + (size_t)idx * D_;
        float p0 = 0.f, p1 = 0.f, p2 = 0.f, p3 = 0.f;
        #pragma unroll
        for (int d = 0; d < D_; d += 4) {
            p0 = fmaf(xf[d],   row[d],   p0); p1 = fmaf(xf[d+1], row[d+1], p1);
            p2 = fmaf(xf[d+2], row[d+2], p2); p3 = fmaf(xf[d+3], row[d+3], p3);
        }
        const float dd = fmaf(-2.f, (p0 + p1) + (p2 + p3), cbn[idx]);
        flag |= (fabsf(dd - bestW[token]) > CONS_EPS) ? 1 : 0;
    }

    // cooperative exact fp32 rescan for flagged tokens
    unsigned long long m = __ballot(flag != 0);
    while (m) {
        const int j = __ffsll(m) - 1; m &= m - 1;
        const int tokj = blockIdx.x * 256 + (tid & ~63) + j;
        float xfj[D_];
        #pragma unroll
        for (int d = 0; d < D_; ++d) xfj[d] = xfT[(size_t)d * NTOK + tokj];
        float bb = 3.4e38f; int bi = 0;
        #pragma unroll
        for (int p = 0; p < 8; ++p) {
            const int c = lane + 64 * p;
            const float* row = cb + (size_t)c * D_;
            float p0 = 0.f, p1 = 0.f, p2 = 0.f, p3 = 0.f;
            #pragma unroll
            for (int d = 0; d < D_; d += 4) {
                p0 = fmaf(xfj[d],   row[d],   p0); p1 = fmaf(xfj[d+1], row[d+1], p1);
                p2 = fmaf(xfj[d+2], row[d+2], p2); p3 = fmaf(xfj[d+3], row[d+3], p3);
            }
            const float dd = fmaf(-2.f, (p0 + p1) + (p2 + p3), cbn[c]);
            if (dd < bb) { bb = dd; bi = c; }
        }
        #pragma unroll
        for (int s = 1; s < 64; s <<= 1) {
            const float ob = __shfl_xor(bb, s); const int oi = __shfl_xor(bi, s);
            if (ob < bb || (ob == bb && oi < bi)) { bb = ob; bi = oi; }
        }
        if (lane == j) idx = bi;
    }

    out[IDX_OFF + token] = (float)idx;

    const float* qrow = cb + (size_t)idx * D_;
    float qv[D_], l = 0.f;
    #pragma unroll
    for (int d = 0; d < D_; ++d) { qv[d] = qrow[d]; const float df = qv[d] - xf[d]; l = fmaf(df, df, l); }

    float* obase = out + (size_t)b * (C_ * HW_) + hw;
    #pragma unroll
    for (int c = 0; c < C_; ++c) {
        float a = pb[c]; const float* pr = pw + c * D_;
        #pragma unroll
        for (int d = 0; d < D_; ++d) a = fmaf(qv[d], pr[d], a);
        obase[(size_t)c * HW_] = a;
    }

    #pragma unroll
    for (int off = 32; off; off >>= 1) l += __shfl_down(l, off);
    const int wid = tid >> 6;
    if (lane == 0) lsum[wid] = l;
    __syncthreads();
    if (tid == 0)
        atomicAdd(out + LOSS_OFF, ((lsum[0] + lsum[1]) + (lsum[2] + lsum[3])) * (2.0f / (float)(NTOK * D_)));
}

// ---------- fallback (round-1 monolithic, correct at ~125 us) ----------
__global__ __launch_bounds__(256)
void vq_mono(const float* __restrict__ z,  const float* __restrict__ qw,
             const float* __restrict__ qb, const float* __restrict__ cb,
             const float* __restrict__ pw, const float* __restrict__ pb,
             float* __restrict__ out)
{
    __shared__ float cbn_s[K_];
    __shared__ float lsum[4];
    const int tid = threadIdx.x;
    for (int k = tid; k < K_; k += 256) {
        const float* row = cb + k * D_;
        float s = 0.f;
        #pragma unroll
        for (int d = 0; d < D_; ++d) s = fmaf(row[d], row[d], s);
        cbn_s[k] = s;
    }
    __syncthreads();
    const int token = blockIdx.x * 256 + tid;
    const int b = token >> 12, hw = token & (HW_ - 1);
    const float* zbase = z + (size_t)b * C_ * HW_ + hw;
    float zv[C_];
    #pragma unroll
    for (int c = 0; c < C_; ++c) zv[c] = zbase[(size_t)c * HW_];
    float xf[D_];
    #pragma unroll
    for (int d = 0; d < D_; ++d) {
        float a = qb[d];
        #pragma unroll
        for (int c = 0; c < C_; ++c) a = fmaf(zv[c], qw[d * C_ + c], a);
        xf[d] = a;
    }
    float best = 3.4e38f; int bi = 0;
    #pragma unroll 2
    for (int k = 0; k < K_; ++k) {
        const float* row = cb + k * D_;
        float p0 = 0.f, p1 = 0.f, p2 = 0.f, p3 = 0.f;
        #pragma unroll
        for (int d = 0; d < D_; d += 4) {
            p0 = fmaf(xf[d+0], row[d+0], p0); p1 = fmaf(xf[d+1], row[d+1], p1);
            p2 = fmaf(xf[d+2], row[d+2], p2); p3 = fmaf(xf[d+3], row[d+3], p3);
        }
        const float s = fmaf(-2.f, (p0+p1)+(p2+p3), cbn_s[k]);
        if (s < best) { best = s; bi = k; }
    }
    out[IDX_OFF + token] = (float)bi;
    const float* qrow = cb + (size_t)bi * D_;
    float qv[D_];
    #pragma unroll
    for (int d = 0; d < D_; ++d) qv[d] = qrow[d];
    float l = 0.f;
    #pragma unroll
    for (int d = 0; d < D_; ++d) { const float df = qv[d] - xf[d]; l = fmaf(df, df, l); }
    float* obase = out + (size_t)b * C_ * HW_ + hw;
    #pragma unroll
    for (int c = 0; c < C_; ++c) {
        float a = pb[c];
        #pragma unroll
        for (int d = 0; d < D_; ++d) a = fmaf(qv[d], pw[c * D_ + d], a);
        obase[(size_t)c * HW_] = a;
    }
    #pragma unroll
    for (int off = 32; off; off >>= 1) l += __shfl_down(l, off);
    const int wid = tid >> 6, lane = tid & 63;
    if (lane == 0) lsum[wid] = l;
    __syncthreads();
    if (tid == 0) {
        const float t = (lsum[0] + lsum[1]) + (lsum[2] + lsum[3]);
        atomicAdd(out + LOSS_OFF, t * (2.0f / (float)(NTOK * D_)));
    }
}

extern "C" void kernel_launch(void* const* d_in, const int* in_sizes, int n_in,
                              void* d_out, int out_size, void* d_ws, size_t ws_size,
                              hipStream_t stream) {
    (void)in_sizes; (void)n_in; (void)out_size;
    const float* z  = (const float*)d_in[0];
    const float* qw = (const float*)d_in[1];
    const float* qb = (const float*)d_in[2];
    const float* cb = (const float*)d_in[3];
    const float* pw = (const float*)d_in[4];
    const float* pb = (const float*)d_in[5];
    float* out = (float*)d_out;

    hipMemsetAsync((char*)d_out + (size_t)LOSS_OFF * sizeof(float), 0, sizeof(float), stream);

    if (ws_size < (size_t)WS_NEEDED) {
        vq_mono<<<NTOK / 256, 256, 0, stream>>>(z, qw, qb, cb, pw, pb, out);
        return;
    }
    char* ws = (char*)d_ws;
    float*          cbn  = (float*)(ws + WS_CBN);
    unsigned short* cbh  = (unsigned short*)(ws + WS_CBH);
    unsigned short* cbl  = (unsigned short*)(ws + WS_CBL);
    unsigned short* xh   = (unsigned short*)(ws + WS_XH);
    unsigned short* xl   = (unsigned short*)(ws + WS_XL);
    float*          xfT  = (float*)(ws + WS_XFT);
    unsigned*       idxf = (unsigned*)(ws + WS_IDXF);
    float*          bstW = (float*)(ws + WS_BESTW);

    prep<<<NTOK / 256, 256, 0, stream>>>(z, qw, qb, cb, cbn, cbh, cbl, xh, xl, xfT);
    scan_mfma<<<NTOK / 128, 256, 0, stream>>>(xh, xl, cbh, cbl, cbn, idxf, bstW);
    combine<<<NTOK / 256, 256, 0, stream>>>(cb, pw, pb, cbn, xfT, idxf, bstW, out);
}